// Round 4
// baseline (231.577 us; speedup 1.0000x reference)
//
#include <hip/hip_runtime.h>

#define BN_EPS 1e-5f
#define ALPHA 0.5f
#define BETA 0.5f

// B=32, C=1024, W=32, H=32, K=2.
// Single fused persistent kernel: fm is read exactly once. Each thread keeps
// its 32 float4s (one 32-channel chunk x 4 spatial positions) in registers
// across the factor dependency, then multiplies and stores both outputs.
//
// ws layout (bytes):
//   conv_w [32][1024] f32 @ 0
//   conv_h [32][1024] f32 @ 131072
//   cnt    [32] uint, 64B stride @ 262144
//   fac    [32][4] float2 @ 264192   (q = kw*2+kh, packed as u64)

typedef float vfloat4 __attribute__((ext_vector_type(4)));
#define SCOPE_AGENT __HIP_MEMORY_SCOPE_AGENT

__global__ __launch_bounds__(256, 2) void k_fused(
    const float* __restrict__ fm, const float* __restrict__ wW,
    const float* __restrict__ wH, const float* __restrict__ bw,
    const float* __restrict__ gw, const float* __restrict__ betw,
    const float* __restrict__ mw, const float* __restrict__ vw,
    const float* __restrict__ bh, const float* __restrict__ gh,
    const float* __restrict__ beth, const float* __restrict__ mh,
    const float* __restrict__ vh, float* __restrict__ conv_w,
    float* __restrict__ conv_h, unsigned int* __restrict__ cnt,
    unsigned long long* __restrict__ fac, float* __restrict__ out0,
    float* __restrict__ out1) {
  __shared__ vfloat4 red[4];
  __shared__ unsigned int s_old;

  const int t = threadIdx.x;        // spatial float4 pos 0..255 (elems 4t..4t+3)
  const int B = blockIdx.x;         // 0..511
  const int c0 = (B & 31) * 32;     // 32-channel chunk

  const vfloat4* fm4 = reinterpret_cast<const vfloat4*>(fm);
  vfloat4* o0 = reinterpret_cast<vfloat4*>(out0);
  vfloat4* o1 = reinterpret_cast<vfloat4*>(out1);

  for (int round = 0; round < 2; ++round) {
    const int b = round * 16 + (B >> 5);
    const size_t base = (size_t)(b * 1024 + c0) * 256 + t;

    // ---- conv phase: load 32 float4s, keep in registers ----
    vfloat4 v[32];
    vfloat4 aw = {0.f, 0.f, 0.f, 0.f};
    vfloat4 ah = {0.f, 0.f, 0.f, 0.f};
#pragma unroll
    for (int c = 0; c < 32; ++c) {
      v[c] = fm4[base + (size_t)c * 256];
      aw += v[c] * wW[c0 + c];
      ah += v[c] * wH[c0 + c];
    }
    {
      float* cwp = conv_w + b * 1024 + t * 4;
      float* chp = conv_h + b * 1024 + t * 4;
      atomicAdd(cwp + 0, aw.x);
      atomicAdd(cwp + 1, aw.y);
      atomicAdd(cwp + 2, aw.z);
      atomicAdd(cwp + 3, aw.w);
      atomicAdd(chp + 0, ah.x);
      atomicAdd(chp + 1, ah.y);
      atomicAdd(chp + 2, ah.z);
      atomicAdd(chp + 3, ah.w);
    }
    __syncthreads();  // drains vmcnt: all this block's atomics are at the
                      // coherent point before the counter bump
    if (t == 0) {
      s_old = __hip_atomic_fetch_add(&cnt[b * 16], 1u, __ATOMIC_ACQ_REL,
                                     SCOPE_AGENT);
    }
    __syncthreads();

    // ---- publisher: last-arriving block computes factors ----
    if (s_old == 31) {
      const int pw_i = b * 1024 + t * 4;
      float cw4[4], ch4[4];
#pragma unroll
      for (int j = 0; j < 4; ++j) {
        cw4[j] = __hip_atomic_load(&conv_w[pw_i + j], __ATOMIC_RELAXED,
                                   SCOPE_AGENT);
        ch4[j] = __hip_atomic_load(&conv_h[pw_i + j], __ATOMIC_RELAXED,
                                   SCOPE_AGENT);
      }
      const float scale_w = gw[0] * rsqrtf(vw[0] + BN_EPS);
      const float shift_w = (bw[0] - mw[0]) * scale_w + betw[0];
      const float scale_h = gh[0] * rsqrtf(vh[0] + BN_EPS);
      const float shift_h = (bh[0] - mh[0]) * scale_h + beth[0];
      float aws = 0.f, ahs = 0.f;
#pragma unroll
      for (int j = 0; j < 4; ++j) {
        aws += fmaxf(fmaf(cw4[j], scale_w, shift_w), 0.f);
        ahs += fmaxf(fmaf(ch4[j], scale_h, shift_h), 0.f);
      }
      // thread t covers elems 4t..4t+3: kw = t>>7, kh = (t&7)>>2
      const int kwq = t >> 7;
      const int khq = (t & 7) >> 2;
      vfloat4 s;
      s.x = kwq ? 0.f : aws;
      s.y = kwq ? aws : 0.f;
      s.z = khq ? 0.f : ahs;
      s.w = khq ? ahs : 0.f;
#pragma unroll
      for (int off = 32; off >= 1; off >>= 1) {
        s.x += __shfl_xor(s.x, off);
        s.y += __shfl_xor(s.y, off);
        s.z += __shfl_xor(s.z, off);
        s.w += __shfl_xor(s.w, off);
      }
      if ((t & 63) == 0) red[t >> 6] = s;
      __syncthreads();
      if (t == 0) {
        const vfloat4 a = red[0] + red[1] + red[2] + red[3];
        const float pw0 = a.x * (1.f / 512.f), pw1 = a.y * (1.f / 512.f);
        const float ph0 = a.z * (1.f / 512.f), ph1 = a.w * (1.f / 512.f);
        const float mwv = fmaxf(pw0, pw1);
        const float ew0 = __expf(pw0 - mwv), ew1 = __expf(pw1 - mwv);
        const float sw0 = ew0 / (ew0 + ew1), sw1 = ew1 / (ew0 + ew1);
        const float mhv = fmaxf(ph0, ph1);
        const float eh0 = __expf(ph0 - mhv), eh1 = __expf(ph1 - mhv);
        const float sh0 = eh0 / (eh0 + eh1), sh1 = eh1 / (eh0 + eh1);
        float f[4];
        f[0] = sw0 * sh0;
        f[1] = sw0 * sh1;
        f[2] = sw1 * sh0;
        f[3] = sw1 * sh1;
        const float thr = fmaxf(fmaxf(f[0], f[1]), fmaxf(f[2], f[3])) * 0.95f;
#pragma unroll
        for (int q = 0; q < 4; ++q) {
          float2 p = make_float2(1.f + ALPHA * f[q], (f[q] < thr) ? 1.f : BETA);
          unsigned long long u;
          __builtin_memcpy(&u, &p, 8);
          __hip_atomic_store(&fac[b * 4 + q], u, __ATOMIC_RELAXED, SCOPE_AGENT);
        }
        __hip_atomic_fetch_add(&cnt[b * 16], 1u, __ATOMIC_RELEASE, SCOPE_AGENT);
      }
    }

    // ---- wait for this batch's factors ----
    while (__hip_atomic_load(&cnt[b * 16], __ATOMIC_ACQUIRE, SCOPE_AGENT) <
           33u) {
      __builtin_amdgcn_s_sleep(10);
    }

    // ---- out phase: multiply retained registers, store both outputs ----
    const int kw = t >> 7;
    const int kh = (t & 7) >> 2;
    const unsigned long long fu = __hip_atomic_load(
        &fac[b * 4 + (kw * 2 + kh)], __ATOMIC_RELAXED, SCOPE_AGENT);
    float2 fp;
    __builtin_memcpy(&fp, &fu, 8);
#pragma unroll
    for (int c = 0; c < 32; ++c) {
      const size_t o = base + (size_t)c * 256;
      __builtin_nontemporal_store(v[c] * fp.x, &o0[o]);
      __builtin_nontemporal_store(v[c] * fp.y, &o1[o]);
    }
  }
}

extern "C" void kernel_launch(void* const* d_in, const int* in_sizes, int n_in,
                              void* d_out, int out_size, void* d_ws,
                              size_t ws_size, hipStream_t stream) {
  const float* fm = (const float*)d_in[0];
  const float* w_w = (const float*)d_in[1];
  const float* b_w = (const float*)d_in[2];
  const float* g_w = (const float*)d_in[3];
  const float* be_w = (const float*)d_in[4];
  const float* m_w = (const float*)d_in[5];
  const float* v_w = (const float*)d_in[6];
  const float* w_h = (const float*)d_in[7];
  const float* b_h = (const float*)d_in[8];
  const float* g_h = (const float*)d_in[9];
  const float* be_h = (const float*)d_in[10];
  const float* m_h = (const float*)d_in[11];
  const float* v_h = (const float*)d_in[12];

  char* ws = (char*)d_ws;
  float* conv_w = (float*)(ws + 0);
  float* conv_h = (float*)(ws + 131072);
  unsigned int* cnt = (unsigned int*)(ws + 262144);
  unsigned long long* fac = (unsigned long long*)(ws + 264192);

  float* out0 = (float*)d_out;
  float* out1 = out0 + (size_t)32 * 1024 * 1024;

  // zero conv accumulators + counters (264192 bytes)
  hipMemsetAsync(d_ws, 0, 264192, stream);

  k_fused<<<512, 256, 0, stream>>>(fm, w_w, w_h, b_w, g_w, be_w, m_w, v_w, b_h,
                                   g_h, be_h, m_h, v_h, conv_w, conv_h, cnt,
                                   fac, out0, out1);
}

// Round 5
// 152.613 us; speedup vs baseline: 1.5174x; 1.5174x over previous
//
#include <hip/hip_runtime.h>

#define BN_EPS 1e-5f
#define ALPHA 0.5f
#define BETA 0.5f

// B=32, C=1024, W=32, H=32, K=2.
// 3 dispatches: memset(2.5KB) -> k_conv (conv+BN+ReLU+pool+softmax, last-block
// publisher emits factors) -> k_out (elementwise, plain stores, reverse order).
//
// ws byte layout:
//   pooled_w [32][2] f32  @ 0     (256 B)
//   pooled_h [32][2] f32  @ 256   (256 B)
//   cnt      [32] u32 x64B @ 512  (2048 B)   <- memset covers 0..2560
//   fac      [32][4] float2 @ 2560 (1024 B)  (written every call by publisher)

typedef float vfloat4 __attribute__((ext_vector_type(4)));
#define SCOPE_AGENT __HIP_MEMORY_SCOPE_AGENT

__global__ __launch_bounds__(256) void k_conv(
    const float* __restrict__ fm, const float* __restrict__ wW,
    const float* __restrict__ wH, const float* __restrict__ bw,
    const float* __restrict__ gw, const float* __restrict__ betw,
    const float* __restrict__ mw, const float* __restrict__ vw,
    const float* __restrict__ bh, const float* __restrict__ gh,
    const float* __restrict__ beth, const float* __restrict__ mh,
    const float* __restrict__ vh, float* __restrict__ pooled_w,
    float* __restrict__ pooled_h, unsigned int* __restrict__ cnt,
    float2* __restrict__ fac) {
  __shared__ float lw[1024];
  __shared__ float lh[1024];
  __shared__ float4 part_w[32][8];
  __shared__ float4 part_h[32][8];

  const int t = threadIdx.x;
  const int b = blockIdx.x >> 5;    // batch
  const int row = blockIdx.x & 31;  // w row

  {
    reinterpret_cast<float4*>(lw)[t] = reinterpret_cast<const float4*>(wW)[t];
    reinterpret_cast<float4*>(lh)[t] = reinterpret_cast<const float4*>(wH)[t];
  }
  __syncthreads();

  const int c_off = t >> 3;  // channel within 32-group
  const int s4 = t & 7;      // float4 within the row (h)
  const vfloat4* f4 = reinterpret_cast<const vfloat4*>(fm) +
                      ((size_t)(b * 1024 + c_off) * 256 + row * 8 + s4);

  vfloat4 aw = {0.f, 0.f, 0.f, 0.f};
  vfloat4 ah = {0.f, 0.f, 0.f, 0.f};
#pragma unroll 8
  for (int it = 0; it < 32; ++it) {
    const int c = it * 32 + c_off;
    const vfloat4 v = f4[(size_t)it * 32 * 256];
    aw += v * lw[c];
    ah += v * lh[c];
  }
  part_w[c_off][s4] = (float4){aw.x, aw.y, aw.z, aw.w};
  part_h[c_off][s4] = (float4){ah.x, ah.y, ah.z, ah.w};
  __syncthreads();

  if (t < 8) {
    const float scale_w = gw[0] * rsqrtf(vw[0] + BN_EPS);
    const float shift_w = (bw[0] - mw[0]) * scale_w + betw[0];
    const float scale_h = gh[0] * rsqrtf(vh[0] + BN_EPS);
    const float shift_h = (bh[0] - mh[0]) * scale_h + beth[0];

    float4 cw = {0.f, 0.f, 0.f, 0.f};
    float4 ch = {0.f, 0.f, 0.f, 0.f};
#pragma unroll
    for (int g = 0; g < 32; ++g) {
      const float4 pw = part_w[g][t];
      const float4 ph = part_h[g][t];
      cw.x += pw.x; cw.y += pw.y; cw.z += pw.z; cw.w += pw.w;
      ch.x += ph.x; ch.y += ph.y; ch.z += ph.z; ch.w += ph.w;
    }
    float aws = fmaxf(fmaf(cw.x, scale_w, shift_w), 0.f) +
                fmaxf(fmaf(cw.y, scale_w, shift_w), 0.f) +
                fmaxf(fmaf(cw.z, scale_w, shift_w), 0.f) +
                fmaxf(fmaf(cw.w, scale_w, shift_w), 0.f);
    const float ahs = fmaxf(fmaf(ch.x, scale_h, shift_h), 0.f) +
                      fmaxf(fmaf(ch.y, scale_h, shift_h), 0.f) +
                      fmaxf(fmaf(ch.z, scale_h, shift_h), 0.f) +
                      fmaxf(fmaf(ch.w, scale_h, shift_h), 0.f);
    // lane t (<8) covers h = 4t..4t+3 -> kh = t>>2
    const int kh = t >> 2;
    float v0 = kh == 0 ? ahs : 0.f;
    float v1 = kh == 1 ? ahs : 0.f;
#pragma unroll
    for (int off = 4; off >= 1; off >>= 1) {
      aws += __shfl_xor(aws, off);
      v0 += __shfl_xor(v0, off);
      v1 += __shfl_xor(v1, off);
    }
    if (t == 0) {
      const int kw = row >> 4;
      atomicAdd(&pooled_w[b * 2 + kw], aws);
      atomicAdd(&pooled_h[b * 2 + 0], v0);
      atomicAdd(&pooled_h[b * 2 + 1], v1);
      const unsigned int old = __hip_atomic_fetch_add(
          &cnt[b * 16], 1u, __ATOMIC_ACQ_REL, SCOPE_AGENT);
      if (old == 31u) {
        // last block for this batch: all 32 rows' adds are visible
        const float pw0 = __hip_atomic_load(&pooled_w[b * 2 + 0],
                                            __ATOMIC_RELAXED, SCOPE_AGENT) *
                          (1.f / 512.f);
        const float pw1 = __hip_atomic_load(&pooled_w[b * 2 + 1],
                                            __ATOMIC_RELAXED, SCOPE_AGENT) *
                          (1.f / 512.f);
        const float ph0 = __hip_atomic_load(&pooled_h[b * 2 + 0],
                                            __ATOMIC_RELAXED, SCOPE_AGENT) *
                          (1.f / 512.f);
        const float ph1 = __hip_atomic_load(&pooled_h[b * 2 + 1],
                                            __ATOMIC_RELAXED, SCOPE_AGENT) *
                          (1.f / 512.f);
        const float mwv = fmaxf(pw0, pw1);
        const float ew0 = __expf(pw0 - mwv), ew1 = __expf(pw1 - mwv);
        const float sw0 = ew0 / (ew0 + ew1), sw1 = ew1 / (ew0 + ew1);
        const float mhv = fmaxf(ph0, ph1);
        const float eh0 = __expf(ph0 - mhv), eh1 = __expf(ph1 - mhv);
        const float sh0 = eh0 / (eh0 + eh1), sh1 = eh1 / (eh0 + eh1);
        float f[4];
        f[0] = sw0 * sh0;
        f[1] = sw0 * sh1;
        f[2] = sw1 * sh0;
        f[3] = sw1 * sh1;
        const float thr =
            fmaxf(fmaxf(f[0], f[1]), fmaxf(f[2], f[3])) * 0.95f;
#pragma unroll
        for (int q = 0; q < 4; ++q) {
          fac[b * 4 + q] =
              make_float2(1.f + ALPHA * f[q], (f[q] < thr) ? 1.f : BETA);
        }
      }
    }
  }
}

// Elementwise output pass. 2048 blocks x 256 threads x 16 float4.
// Segments processed in reverse so the fm re-read chases the freshest
// L3 lines left by k_conv. Plain (allocating) stores — NT removed.
__global__ __launch_bounds__(256) void k_out(
    const float* __restrict__ fm, const float2* __restrict__ fac,
    float* __restrict__ out0, float* __restrict__ out1) {
  const int t = threadIdx.x;
  const vfloat4* fm4 = reinterpret_cast<const vfloat4*>(fm);
  vfloat4* o0 = reinterpret_cast<vfloat4*>(out0);
  vfloat4* o1 = reinterpret_cast<vfloat4*>(out1);
#pragma unroll 4
  for (int c = 0; c < 16; ++c) {
    const int seg = 32767 - (c * 2048 + (int)blockIdx.x);
    const size_t i = (size_t)seg * 256 + t;
    // elem e = 4i: b = i>>18, kw = bit7(i), kh = bit2(i)
    const int idx = (((int)(i >> 18)) << 2) | ((((int)i >> 7) & 1) << 1) |
                    (((int)i >> 2) & 1);
    const float2 f = fac[idx];
    const vfloat4 v = fm4[i];
    o0[i] = v * f.x;
    o1[i] = v * f.y;
  }
}

extern "C" void kernel_launch(void* const* d_in, const int* in_sizes, int n_in,
                              void* d_out, int out_size, void* d_ws,
                              size_t ws_size, hipStream_t stream) {
  const float* fm = (const float*)d_in[0];
  const float* w_w = (const float*)d_in[1];
  const float* b_w = (const float*)d_in[2];
  const float* g_w = (const float*)d_in[3];
  const float* be_w = (const float*)d_in[4];
  const float* m_w = (const float*)d_in[5];
  const float* v_w = (const float*)d_in[6];
  const float* w_h = (const float*)d_in[7];
  const float* b_h = (const float*)d_in[8];
  const float* g_h = (const float*)d_in[9];
  const float* be_h = (const float*)d_in[10];
  const float* m_h = (const float*)d_in[11];
  const float* v_h = (const float*)d_in[12];

  char* ws = (char*)d_ws;
  float* pooled_w = (float*)(ws + 0);
  float* pooled_h = (float*)(ws + 256);
  unsigned int* cnt = (unsigned int*)(ws + 512);
  float2* fac = (float2*)(ws + 2560);

  float* out0 = (float*)d_out;
  float* out1 = out0 + (size_t)32 * 1024 * 1024;

  hipMemsetAsync(d_ws, 0, 2560, stream);

  k_conv<<<32 * 32, 256, 0, stream>>>(fm, w_w, w_h, b_w, g_w, be_w, m_w, v_w,
                                      b_h, g_h, be_h, m_h, v_h, pooled_w,
                                      pooled_h, cnt, fac);
  k_out<<<2048, 256, 0, stream>>>(fm, fac, out0, out1);
}

// Round 6
// 146.286 us; speedup vs baseline: 1.5830x; 1.0433x over previous
//
#include <hip/hip_runtime.h>

#define BN_EPS 1e-5f
#define ALPHA 0.5f
#define BETA 0.5f

// B=32, C=1024, W=32, H=32, K=2.
// 3 dispatches: memset(2.5KB) -> k_conv (conv+BN+ReLU+pool+softmax, last-block
// publisher emits factors) -> k_out (elementwise, plain stores, forward order).
//
// ws byte layout:
//   pooled_w [32][2] f32  @ 0     (256 B)
//   pooled_h [32][2] f32  @ 256   (256 B)
//   cnt      [32] u32 x64B @ 512  (2048 B)   <- memset covers 0..2560
//   fac      [32][4] float2 @ 2560 (1024 B)  (fully rewritten every call)

typedef float vfloat4 __attribute__((ext_vector_type(4)));
#define SCOPE_AGENT __HIP_MEMORY_SCOPE_AGENT

__global__ __launch_bounds__(256) void k_conv(
    const float* __restrict__ fm, const float* __restrict__ wW,
    const float* __restrict__ wH, const float* __restrict__ bw,
    const float* __restrict__ gw, const float* __restrict__ betw,
    const float* __restrict__ mw, const float* __restrict__ vw,
    const float* __restrict__ bh, const float* __restrict__ gh,
    const float* __restrict__ beth, const float* __restrict__ mh,
    const float* __restrict__ vh, float* __restrict__ pooled_w,
    float* __restrict__ pooled_h, unsigned int* __restrict__ cnt,
    float2* __restrict__ fac) {
  __shared__ float lw[1024];
  __shared__ float lh[1024];
  __shared__ float4 part_w[32][8];
  __shared__ float4 part_h[32][8];

  const int t = threadIdx.x;
  const int b = blockIdx.x >> 5;    // batch
  const int row = blockIdx.x & 31;  // w row

  {
    reinterpret_cast<float4*>(lw)[t] = reinterpret_cast<const float4*>(wW)[t];
    reinterpret_cast<float4*>(lh)[t] = reinterpret_cast<const float4*>(wH)[t];
  }
  __syncthreads();

  const int c_off = t >> 3;  // channel within 32-group
  const int s4 = t & 7;      // float4 within the row (h)
  const vfloat4* f4 = reinterpret_cast<const vfloat4*>(fm) +
                      ((size_t)(b * 1024 + c_off) * 256 + row * 8 + s4);

  vfloat4 aw = {0.f, 0.f, 0.f, 0.f};
  vfloat4 ah = {0.f, 0.f, 0.f, 0.f};
#pragma unroll 8
  for (int it = 0; it < 32; ++it) {
    const int c = it * 32 + c_off;
    const vfloat4 v = f4[(size_t)it * 32 * 256];
    aw += v * lw[c];
    ah += v * lh[c];
  }
  part_w[c_off][s4] = (float4){aw.x, aw.y, aw.z, aw.w};
  part_h[c_off][s4] = (float4){ah.x, ah.y, ah.z, ah.w};
  __syncthreads();

  if (t < 8) {
    const float scale_w = gw[0] * rsqrtf(vw[0] + BN_EPS);
    const float shift_w = (bw[0] - mw[0]) * scale_w + betw[0];
    const float scale_h = gh[0] * rsqrtf(vh[0] + BN_EPS);
    const float shift_h = (bh[0] - mh[0]) * scale_h + beth[0];

    float4 cw = {0.f, 0.f, 0.f, 0.f};
    float4 ch = {0.f, 0.f, 0.f, 0.f};
#pragma unroll
    for (int g = 0; g < 32; ++g) {
      const float4 pw = part_w[g][t];
      const float4 ph = part_h[g][t];
      cw.x += pw.x; cw.y += pw.y; cw.z += pw.z; cw.w += pw.w;
      ch.x += ph.x; ch.y += ph.y; ch.z += ph.z; ch.w += ph.w;
    }
    float aws = fmaxf(fmaf(cw.x, scale_w, shift_w), 0.f) +
                fmaxf(fmaf(cw.y, scale_w, shift_w), 0.f) +
                fmaxf(fmaf(cw.z, scale_w, shift_w), 0.f) +
                fmaxf(fmaf(cw.w, scale_w, shift_w), 0.f);
    const float ahs = fmaxf(fmaf(ch.x, scale_h, shift_h), 0.f) +
                      fmaxf(fmaf(ch.y, scale_h, shift_h), 0.f) +
                      fmaxf(fmaf(ch.z, scale_h, shift_h), 0.f) +
                      fmaxf(fmaf(ch.w, scale_h, shift_h), 0.f);
    // lane t (<8) covers h = 4t..4t+3 -> kh = t>>2
    const int kh = t >> 2;
    float v0 = kh == 0 ? ahs : 0.f;
    float v1 = kh == 1 ? ahs : 0.f;
#pragma unroll
    for (int off = 4; off >= 1; off >>= 1) {
      aws += __shfl_xor(aws, off);
      v0 += __shfl_xor(v0, off);
      v1 += __shfl_xor(v1, off);
    }
    if (t == 0) {
      const int kw = row >> 4;
      atomicAdd(&pooled_w[b * 2 + kw], aws);
      atomicAdd(&pooled_h[b * 2 + 0], v0);
      atomicAdd(&pooled_h[b * 2 + 1], v1);
      const unsigned int old = __hip_atomic_fetch_add(
          &cnt[b * 16], 1u, __ATOMIC_ACQ_REL, SCOPE_AGENT);
      if (old == 31u) {
        // last block for this batch: all 32 rows' adds are visible
        const float pw0 = __hip_atomic_load(&pooled_w[b * 2 + 0],
                                            __ATOMIC_RELAXED, SCOPE_AGENT) *
                          (1.f / 512.f);
        const float pw1 = __hip_atomic_load(&pooled_w[b * 2 + 1],
                                            __ATOMIC_RELAXED, SCOPE_AGENT) *
                          (1.f / 512.f);
        const float ph0 = __hip_atomic_load(&pooled_h[b * 2 + 0],
                                            __ATOMIC_RELAXED, SCOPE_AGENT) *
                          (1.f / 512.f);
        const float ph1 = __hip_atomic_load(&pooled_h[b * 2 + 1],
                                            __ATOMIC_RELAXED, SCOPE_AGENT) *
                          (1.f / 512.f);
        const float mwv = fmaxf(pw0, pw1);
        const float ew0 = __expf(pw0 - mwv), ew1 = __expf(pw1 - mwv);
        const float sw0 = ew0 / (ew0 + ew1), sw1 = ew1 / (ew0 + ew1);
        const float mhv = fmaxf(ph0, ph1);
        const float eh0 = __expf(ph0 - mhv), eh1 = __expf(ph1 - mhv);
        const float sh0 = eh0 / (eh0 + eh1), sh1 = eh1 / (eh0 + eh1);
        float f[4];
        f[0] = sw0 * sh0;
        f[1] = sw0 * sh1;
        f[2] = sw1 * sh0;
        f[3] = sw1 * sh1;
        const float thr =
            fmaxf(fmaxf(f[0], f[1]), fmaxf(f[2], f[3])) * 0.95f;
#pragma unroll
        for (int q = 0; q < 4; ++q) {
          fac[b * 4 + q] =
              make_float2(1.f + ALPHA * f[q], (f[q] < thr) ? 1.f : BETA);
        }
      }
    }
  }
}

// Elementwise output pass. 8192 blocks x 256 threads x 4 float4 (R1 geometry,
// forward order), plain allocating stores.
__global__ __launch_bounds__(256) void k_out(
    const float* __restrict__ fm, const float2* __restrict__ fac,
    float* __restrict__ out0, float* __restrict__ out1) {
  const size_t i0 = (size_t)blockIdx.x * 256 + threadIdx.x;
  const vfloat4* fm4 = reinterpret_cast<const vfloat4*>(fm);
  vfloat4* o0 = reinterpret_cast<vfloat4*>(out0);
  vfloat4* o1 = reinterpret_cast<vfloat4*>(out1);
#pragma unroll
  for (int k = 0; k < 4; ++k) {
    const size_t i = i0 + (size_t)k * 2097152;
    // elem e = 4i: b = i>>18, kw = bit7(i), kh = bit2(i)
    const int idx = (((int)(i >> 18)) << 2) | ((((int)i >> 7) & 1) << 1) |
                    (((int)i >> 2) & 1);
    const float2 f = fac[idx];
    const vfloat4 v = fm4[i];
    o0[i] = v * f.x;
    o1[i] = v * f.y;
  }
}

extern "C" void kernel_launch(void* const* d_in, const int* in_sizes, int n_in,
                              void* d_out, int out_size, void* d_ws,
                              size_t ws_size, hipStream_t stream) {
  const float* fm = (const float*)d_in[0];
  const float* w_w = (const float*)d_in[1];
  const float* b_w = (const float*)d_in[2];
  const float* g_w = (const float*)d_in[3];
  const float* be_w = (const float*)d_in[4];
  const float* m_w = (const float*)d_in[5];
  const float* v_w = (const float*)d_in[6];
  const float* w_h = (const float*)d_in[7];
  const float* b_h = (const float*)d_in[8];
  const float* g_h = (const float*)d_in[9];
  const float* be_h = (const float*)d_in[10];
  const float* m_h = (const float*)d_in[11];
  const float* v_h = (const float*)d_in[12];

  char* ws = (char*)d_ws;
  float* pooled_w = (float*)(ws + 0);
  float* pooled_h = (float*)(ws + 256);
  unsigned int* cnt = (unsigned int*)(ws + 512);
  float2* fac = (float2*)(ws + 2560);

  float* out0 = (float*)d_out;
  float* out1 = out0 + (size_t)32 * 1024 * 1024;

  hipMemsetAsync(d_ws, 0, 2560, stream);

  k_conv<<<32 * 32, 256, 0, stream>>>(fm, w_w, w_h, b_w, g_w, be_w, m_w, v_w,
                                      b_h, g_h, be_h, m_h, v_h, pooled_w,
                                      pooled_h, cnt, fac);
  k_out<<<8192, 256, 0, stream>>>(fm, fac, out0, out1);
}

// Round 7
// 125.345 us; speedup vs baseline: 1.8475x; 1.1671x over previous
//
#include <hip/hip_runtime.h>

#define BN_EPS 1e-5f
#define ALPHA 0.5f
#define BETA 0.5f

// B=32, C=1024, W=32, H=32, K=2.
// 3 dispatches: memset(2.5KB) -> k_conv (conv+BN+ReLU+pool+softmax, last-block
// publisher emits factors) -> k_out (elementwise, NT stores, forward order).
//
// ws byte layout:
//   pooled_w [32][2] f32  @ 0     (256 B)
//   pooled_h [32][2] f32  @ 256   (256 B)
//   cnt      [32] u32 x64B @ 512  (2048 B)   <- memset covers 0..2560
//   fac      [32][4] float2 @ 2560 (1024 B)  (fully rewritten every call)

typedef float vfloat4 __attribute__((ext_vector_type(4)));
#define SCOPE_AGENT __HIP_MEMORY_SCOPE_AGENT

__global__ __launch_bounds__(256) void k_conv(
    const float* __restrict__ fm, const float* __restrict__ wW,
    const float* __restrict__ wH, const float* __restrict__ bw,
    const float* __restrict__ gw, const float* __restrict__ betw,
    const float* __restrict__ mw, const float* __restrict__ vw,
    const float* __restrict__ bh, const float* __restrict__ gh,
    const float* __restrict__ beth, const float* __restrict__ mh,
    const float* __restrict__ vh, float* __restrict__ pooled_w,
    float* __restrict__ pooled_h, unsigned int* __restrict__ cnt,
    float2* __restrict__ fac) {
  __shared__ float lw[1024];
  __shared__ float lh[1024];
  __shared__ float4 part_w[32][8];
  __shared__ float4 part_h[32][8];

  const int t = threadIdx.x;
  const int b = blockIdx.x >> 5;    // batch
  const int row = blockIdx.x & 31;  // w row

  {
    reinterpret_cast<float4*>(lw)[t] = reinterpret_cast<const float4*>(wW)[t];
    reinterpret_cast<float4*>(lh)[t] = reinterpret_cast<const float4*>(wH)[t];
  }
  __syncthreads();

  const int c_off = t >> 3;  // channel within 32-group
  const int s4 = t & 7;      // float4 within the row (h)
  const vfloat4* f4 = reinterpret_cast<const vfloat4*>(fm) +
                      ((size_t)(b * 1024 + c_off) * 256 + row * 8 + s4);

  vfloat4 aw = {0.f, 0.f, 0.f, 0.f};
  vfloat4 ah = {0.f, 0.f, 0.f, 0.f};
#pragma unroll 8
  for (int it = 0; it < 32; ++it) {
    const int c = it * 32 + c_off;
    const vfloat4 v = f4[(size_t)it * 32 * 256];
    aw += v * lw[c];
    ah += v * lh[c];
  }
  part_w[c_off][s4] = (float4){aw.x, aw.y, aw.z, aw.w};
  part_h[c_off][s4] = (float4){ah.x, ah.y, ah.z, ah.w};
  __syncthreads();

  if (t < 8) {
    const float scale_w = gw[0] * rsqrtf(vw[0] + BN_EPS);
    const float shift_w = (bw[0] - mw[0]) * scale_w + betw[0];
    const float scale_h = gh[0] * rsqrtf(vh[0] + BN_EPS);
    const float shift_h = (bh[0] - mh[0]) * scale_h + beth[0];

    float4 cw = {0.f, 0.f, 0.f, 0.f};
    float4 ch = {0.f, 0.f, 0.f, 0.f};
#pragma unroll
    for (int g = 0; g < 32; ++g) {
      const float4 pw = part_w[g][t];
      const float4 ph = part_h[g][t];
      cw.x += pw.x; cw.y += pw.y; cw.z += pw.z; cw.w += pw.w;
      ch.x += ph.x; ch.y += ph.y; ch.z += ph.z; ch.w += ph.w;
    }
    float aws = fmaxf(fmaf(cw.x, scale_w, shift_w), 0.f) +
                fmaxf(fmaf(cw.y, scale_w, shift_w), 0.f) +
                fmaxf(fmaf(cw.z, scale_w, shift_w), 0.f) +
                fmaxf(fmaf(cw.w, scale_w, shift_w), 0.f);
    const float ahs = fmaxf(fmaf(ch.x, scale_h, shift_h), 0.f) +
                      fmaxf(fmaf(ch.y, scale_h, shift_h), 0.f) +
                      fmaxf(fmaf(ch.z, scale_h, shift_h), 0.f) +
                      fmaxf(fmaf(ch.w, scale_h, shift_h), 0.f);
    // lane t (<8) covers h = 4t..4t+3 -> kh = t>>2
    const int kh = t >> 2;
    float v0 = kh == 0 ? ahs : 0.f;
    float v1 = kh == 1 ? ahs : 0.f;
#pragma unroll
    for (int off = 4; off >= 1; off >>= 1) {
      aws += __shfl_xor(aws, off);
      v0 += __shfl_xor(v0, off);
      v1 += __shfl_xor(v1, off);
    }
    if (t == 0) {
      const int kw = row >> 4;
      atomicAdd(&pooled_w[b * 2 + kw], aws);
      atomicAdd(&pooled_h[b * 2 + 0], v0);
      atomicAdd(&pooled_h[b * 2 + 1], v1);
      const unsigned int old = __hip_atomic_fetch_add(
          &cnt[b * 16], 1u, __ATOMIC_ACQ_REL, SCOPE_AGENT);
      if (old == 31u) {
        // last block for this batch: all 32 rows' adds are visible
        const float pw0 = __hip_atomic_load(&pooled_w[b * 2 + 0],
                                            __ATOMIC_RELAXED, SCOPE_AGENT) *
                          (1.f / 512.f);
        const float pw1 = __hip_atomic_load(&pooled_w[b * 2 + 1],
                                            __ATOMIC_RELAXED, SCOPE_AGENT) *
                          (1.f / 512.f);
        const float ph0 = __hip_atomic_load(&pooled_h[b * 2 + 0],
                                            __ATOMIC_RELAXED, SCOPE_AGENT) *
                          (1.f / 512.f);
        const float ph1 = __hip_atomic_load(&pooled_h[b * 2 + 1],
                                            __ATOMIC_RELAXED, SCOPE_AGENT) *
                          (1.f / 512.f);
        const float mwv = fmaxf(pw0, pw1);
        const float ew0 = __expf(pw0 - mwv), ew1 = __expf(pw1 - mwv);
        const float sw0 = ew0 / (ew0 + ew1), sw1 = ew1 / (ew0 + ew1);
        const float mhv = fmaxf(ph0, ph1);
        const float eh0 = __expf(ph0 - mhv), eh1 = __expf(ph1 - mhv);
        const float sh0 = eh0 / (eh0 + eh1), sh1 = eh1 / (eh0 + eh1);
        float f[4];
        f[0] = sw0 * sh0;
        f[1] = sw0 * sh1;
        f[2] = sw1 * sh0;
        f[3] = sw1 * sh1;
        const float thr =
            fmaxf(fmaxf(f[0], f[1]), fmaxf(f[2], f[3])) * 0.95f;
#pragma unroll
        for (int q = 0; q < 4; ++q) {
          fac[b * 4 + q] =
              make_float2(1.f + ALPHA * f[q], (f[q] < thr) ? 1.f : BETA);
        }
      }
    }
  }
}

// Elementwise output pass. 8192 blocks x 256 threads x 4 float4 (R1 geometry,
// forward order), nontemporal stores (A/B proven: NT is ~43us faster than
// plain — plain stores thrash L2/MALL against the fm read stream).
__global__ __launch_bounds__(256) void k_out(
    const float* __restrict__ fm, const float2* __restrict__ fac,
    float* __restrict__ out0, float* __restrict__ out1) {
  const size_t i0 = (size_t)blockIdx.x * 256 + threadIdx.x;
  const vfloat4* fm4 = reinterpret_cast<const vfloat4*>(fm);
  vfloat4* o0 = reinterpret_cast<vfloat4*>(out0);
  vfloat4* o1 = reinterpret_cast<vfloat4*>(out1);
#pragma unroll
  for (int k = 0; k < 4; ++k) {
    const size_t i = i0 + (size_t)k * 2097152;
    // elem e = 4i: b = i>>18, kw = bit7(i), kh = bit2(i)
    const int idx = (((int)(i >> 18)) << 2) | ((((int)i >> 7) & 1) << 1) |
                    (((int)i >> 2) & 1);
    const float2 f = fac[idx];
    const vfloat4 v = fm4[i];
    __builtin_nontemporal_store(v * f.x, &o0[i]);
    __builtin_nontemporal_store(v * f.y, &o1[i]);
  }
}

extern "C" void kernel_launch(void* const* d_in, const int* in_sizes, int n_in,
                              void* d_out, int out_size, void* d_ws,
                              size_t ws_size, hipStream_t stream) {
  const float* fm = (const float*)d_in[0];
  const float* w_w = (const float*)d_in[1];
  const float* b_w = (const float*)d_in[2];
  const float* g_w = (const float*)d_in[3];
  const float* be_w = (const float*)d_in[4];
  const float* m_w = (const float*)d_in[5];
  const float* v_w = (const float*)d_in[6];
  const float* w_h = (const float*)d_in[7];
  const float* b_h = (const float*)d_in[8];
  const float* g_h = (const float*)d_in[9];
  const float* be_h = (const float*)d_in[10];
  const float* m_h = (const float*)d_in[11];
  const float* v_h = (const float*)d_in[12];

  char* ws = (char*)d_ws;
  float* pooled_w = (float*)(ws + 0);
  float* pooled_h = (float*)(ws + 256);
  unsigned int* cnt = (unsigned int*)(ws + 512);
  float2* fac = (float2*)(ws + 2560);

  float* out0 = (float*)d_out;
  float* out1 = out0 + (size_t)32 * 1024 * 1024;

  hipMemsetAsync(d_ws, 0, 2560, stream);

  k_conv<<<32 * 32, 256, 0, stream>>>(fm, w_w, w_h, b_w, g_w, be_w, m_w, v_w,
                                      b_h, g_h, be_h, m_h, v_h, pooled_w,
                                      pooled_h, cnt, fac);
  k_out<<<8192, 256, 0, stream>>>(fm, fac, out0, out1);
}

// Round 8
// 98.769 us; speedup vs baseline: 2.3446x; 1.2691x over previous
//
#include <hip/hip_runtime.h>

#define BN_EPS 1e-5f
#define ALPHA 0.5f
#define BETA 0.5f

// B=32, C=1024, W=32, H=32, K=2.
// 3 dispatches, no memset, no atomics:
//   k_conv    : conv(C->1) + BN + ReLU + per-(b,row) partial strip sums,
//               one plain float4 store per block -> part[b*32+row]
//   k_factors : per-batch reduce of 32 row-partials + 2-way softmaxes ->
//               fac[b][4] = (boost, mask)
//   k_out     : elementwise, NT stores (A/B: NT ~43us faster than plain),
//               NT loads (probe this round)
//
// ws byte layout:
//   part [32*32] float4 @ 0      (16 KB)  {row_w_sum, h0_sum, h1_sum, 0}
//   fac  [32][4] float2 @ 16384  (1 KB)

typedef float vfloat4 __attribute__((ext_vector_type(4)));

__global__ __launch_bounds__(256) void k_conv(
    const float* __restrict__ fm, const float* __restrict__ wW,
    const float* __restrict__ wH, const float* __restrict__ bw,
    const float* __restrict__ gw, const float* __restrict__ betw,
    const float* __restrict__ mw, const float* __restrict__ vw,
    const float* __restrict__ bh, const float* __restrict__ gh,
    const float* __restrict__ beth, const float* __restrict__ mh,
    const float* __restrict__ vh, float4* __restrict__ part) {
  __shared__ float lw[1024];
  __shared__ float lh[1024];
  __shared__ float4 part_w[32][8];
  __shared__ float4 part_h[32][8];

  const int t = threadIdx.x;
  const int b = blockIdx.x >> 5;    // batch
  const int row = blockIdx.x & 31;  // w row

  {
    reinterpret_cast<float4*>(lw)[t] = reinterpret_cast<const float4*>(wW)[t];
    reinterpret_cast<float4*>(lh)[t] = reinterpret_cast<const float4*>(wH)[t];
  }
  __syncthreads();

  const int c_off = t >> 3;  // channel within 32-group
  const int s4 = t & 7;      // float4 within the row (h)
  const vfloat4* f4 = reinterpret_cast<const vfloat4*>(fm) +
                      ((size_t)(b * 1024 + c_off) * 256 + row * 8 + s4);

  vfloat4 aw = {0.f, 0.f, 0.f, 0.f};
  vfloat4 ah = {0.f, 0.f, 0.f, 0.f};
#pragma unroll 8
  for (int it = 0; it < 32; ++it) {
    const int c = it * 32 + c_off;
    const vfloat4 v = f4[(size_t)it * 32 * 256];
    aw += v * lw[c];
    ah += v * lh[c];
  }
  part_w[c_off][s4] = (float4){aw.x, aw.y, aw.z, aw.w};
  part_h[c_off][s4] = (float4){ah.x, ah.y, ah.z, ah.w};
  __syncthreads();

  if (t < 8) {
    const float scale_w = gw[0] * rsqrtf(vw[0] + BN_EPS);
    const float shift_w = (bw[0] - mw[0]) * scale_w + betw[0];
    const float scale_h = gh[0] * rsqrtf(vh[0] + BN_EPS);
    const float shift_h = (bh[0] - mh[0]) * scale_h + beth[0];

    float4 cw = {0.f, 0.f, 0.f, 0.f};
    float4 ch = {0.f, 0.f, 0.f, 0.f};
#pragma unroll
    for (int g = 0; g < 32; ++g) {
      const float4 pw = part_w[g][t];
      const float4 ph = part_h[g][t];
      cw.x += pw.x; cw.y += pw.y; cw.z += pw.z; cw.w += pw.w;
      ch.x += ph.x; ch.y += ph.y; ch.z += ph.z; ch.w += ph.w;
    }
    float aws = fmaxf(fmaf(cw.x, scale_w, shift_w), 0.f) +
                fmaxf(fmaf(cw.y, scale_w, shift_w), 0.f) +
                fmaxf(fmaf(cw.z, scale_w, shift_w), 0.f) +
                fmaxf(fmaf(cw.w, scale_w, shift_w), 0.f);
    const float ahs = fmaxf(fmaf(ch.x, scale_h, shift_h), 0.f) +
                      fmaxf(fmaf(ch.y, scale_h, shift_h), 0.f) +
                      fmaxf(fmaf(ch.z, scale_h, shift_h), 0.f) +
                      fmaxf(fmaf(ch.w, scale_h, shift_h), 0.f);
    // lane t (<8) covers h = 4t..4t+3 -> kh = t>>2
    const int kh = t >> 2;
    float v0 = kh == 0 ? ahs : 0.f;
    float v1 = kh == 1 ? ahs : 0.f;
#pragma unroll
    for (int off = 4; off >= 1; off >>= 1) {
      aws += __shfl_xor(aws, off);
      v0 += __shfl_xor(v0, off);
      v1 += __shfl_xor(v1, off);
    }
    if (t == 0) {
      part[b * 32 + row] = (float4){aws, v0, v1, 0.f};  // plain store
    }
  }
}

// One block per batch: reduce 32 row-partials, softmax, emit factors.
__global__ __launch_bounds__(64) void k_factors(
    const float4* __restrict__ part, float2* __restrict__ fac) {
  const int b = blockIdx.x;
  const int l = threadIdx.x;  // 0..63
  float sw0 = 0.f, sw1 = 0.f, h0 = 0.f, h1 = 0.f;
  if (l < 32) {
    const float4 p = part[b * 32 + l];
    if (l < 16) sw0 = p.x; else sw1 = p.x;
    h0 = p.y;
    h1 = p.z;
  }
#pragma unroll
  for (int off = 32; off >= 1; off >>= 1) {
    sw0 += __shfl_xor(sw0, off);
    sw1 += __shfl_xor(sw1, off);
    h0 += __shfl_xor(h0, off);
    h1 += __shfl_xor(h1, off);
  }
  if (l == 0) {
    const float pw0 = sw0 * (1.f / 512.f), pw1 = sw1 * (1.f / 512.f);
    const float ph0 = h0 * (1.f / 512.f), ph1 = h1 * (1.f / 512.f);
    const float mwv = fmaxf(pw0, pw1);
    const float ew0 = __expf(pw0 - mwv), ew1 = __expf(pw1 - mwv);
    const float s0 = ew0 / (ew0 + ew1), s1 = ew1 / (ew0 + ew1);
    const float mhv = fmaxf(ph0, ph1);
    const float eh0 = __expf(ph0 - mhv), eh1 = __expf(ph1 - mhv);
    const float t0 = eh0 / (eh0 + eh1), t1 = eh1 / (eh0 + eh1);
    float f[4];
    f[0] = s0 * t0;
    f[1] = s0 * t1;
    f[2] = s1 * t0;
    f[3] = s1 * t1;
    const float thr = fmaxf(fmaxf(f[0], f[1]), fmaxf(f[2], f[3])) * 0.95f;
#pragma unroll
    for (int q = 0; q < 4; ++q) {
      fac[b * 4 + q] =
          make_float2(1.f + ALPHA * f[q], (f[q] < thr) ? 1.f : BETA);
    }
  }
}

// Elementwise output pass. 8192 blocks x 256 threads x 4 float4, forward,
// NT stores; NT loads are this round's probe variable.
__global__ __launch_bounds__(256) void k_out(
    const float* __restrict__ fm, const float2* __restrict__ fac,
    float* __restrict__ out0, float* __restrict__ out1) {
  const size_t i0 = (size_t)blockIdx.x * 256 + threadIdx.x;
  const vfloat4* fm4 = reinterpret_cast<const vfloat4*>(fm);
  vfloat4* o0 = reinterpret_cast<vfloat4*>(out0);
  vfloat4* o1 = reinterpret_cast<vfloat4*>(out1);
#pragma unroll
  for (int k = 0; k < 4; ++k) {
    const size_t i = i0 + (size_t)k * 2097152;
    // elem e = 4i: b = i>>18, kw = bit7(i), kh = bit2(i)
    const int idx = (((int)(i >> 18)) << 2) | ((((int)i >> 7) & 1) << 1) |
                    (((int)i >> 2) & 1);
    const float2 f = fac[idx];
    const vfloat4 v = __builtin_nontemporal_load(&fm4[i]);
    __builtin_nontemporal_store(v * f.x, &o0[i]);
    __builtin_nontemporal_store(v * f.y, &o1[i]);
  }
}

extern "C" void kernel_launch(void* const* d_in, const int* in_sizes, int n_in,
                              void* d_out, int out_size, void* d_ws,
                              size_t ws_size, hipStream_t stream) {
  const float* fm = (const float*)d_in[0];
  const float* w_w = (const float*)d_in[1];
  const float* b_w = (const float*)d_in[2];
  const float* g_w = (const float*)d_in[3];
  const float* be_w = (const float*)d_in[4];
  const float* m_w = (const float*)d_in[5];
  const float* v_w = (const float*)d_in[6];
  const float* w_h = (const float*)d_in[7];
  const float* b_h = (const float*)d_in[8];
  const float* g_h = (const float*)d_in[9];
  const float* be_h = (const float*)d_in[10];
  const float* m_h = (const float*)d_in[11];
  const float* v_h = (const float*)d_in[12];

  char* ws = (char*)d_ws;
  float4* part = (float4*)(ws + 0);       // 16 KB, fully rewritten each call
  float2* fac = (float2*)(ws + 16384);    // 1 KB, fully rewritten each call

  float* out0 = (float*)d_out;
  float* out1 = out0 + (size_t)32 * 1024 * 1024;

  k_conv<<<32 * 32, 256, 0, stream>>>(fm, w_w, w_h, b_w, g_w, be_w, m_w, v_w,
                                      b_h, g_h, be_h, m_h, v_h, part);
  k_factors<<<32, 64, 0, stream>>>(part, fac);
  k_out<<<8192, 256, 0, stream>>>(fm, fac, out0, out1);
}

// Round 9
// 93.372 us; speedup vs baseline: 2.4802x; 1.0578x over previous
//
#include <hip/hip_runtime.h>

#define BN_EPS 1e-5f
#define ALPHA 0.5f
#define BETA 0.5f

// B=32, C=1024, W=32, H=32, K=2.
// 3 dispatches, no memset, no atomics:
//   k_conv    : conv(C->1) + BN + ReLU + per-(b,row) partial strip sums,
//               one plain float4 store per block -> part[b*32+row]
//   k_factors : per-batch reduce of 32 row-partials + 2-way softmaxes ->
//               fac[b][4] = (boost, mask)
//   k_out     : elementwise, NT load/store, block-contiguous 16KB spans
//
// ws byte layout:
//   part [32*32] float4 @ 0      (16 KB)  {row_w_sum, h0_sum, h1_sum, 0}
//   fac  [32][4] float2 @ 16384  (1 KB)

typedef float vfloat4 __attribute__((ext_vector_type(4)));

__global__ __launch_bounds__(256) void k_conv(
    const float* __restrict__ fm, const float* __restrict__ wW,
    const float* __restrict__ wH, const float* __restrict__ bw,
    const float* __restrict__ gw, const float* __restrict__ betw,
    const float* __restrict__ mw, const float* __restrict__ vw,
    const float* __restrict__ bh, const float* __restrict__ gh,
    const float* __restrict__ beth, const float* __restrict__ mh,
    const float* __restrict__ vh, float4* __restrict__ part) {
  __shared__ float lw[1024];
  __shared__ float lh[1024];
  __shared__ float4 part_w[32][8];
  __shared__ float4 part_h[32][8];

  const int t = threadIdx.x;
  const int b = blockIdx.x >> 5;    // batch
  const int row = blockIdx.x & 31;  // w row

  {
    reinterpret_cast<float4*>(lw)[t] = reinterpret_cast<const float4*>(wW)[t];
    reinterpret_cast<float4*>(lh)[t] = reinterpret_cast<const float4*>(wH)[t];
  }
  __syncthreads();

  const int c_off = t >> 3;  // channel within 32-group
  const int s4 = t & 7;      // float4 within the row (h)
  const vfloat4* f4 = reinterpret_cast<const vfloat4*>(fm) +
                      ((size_t)(b * 1024 + c_off) * 256 + row * 8 + s4);

  vfloat4 aw = {0.f, 0.f, 0.f, 0.f};
  vfloat4 ah = {0.f, 0.f, 0.f, 0.f};
#pragma unroll 8
  for (int it = 0; it < 32; ++it) {
    const int c = it * 32 + c_off;
    const vfloat4 v = f4[(size_t)it * 32 * 256];
    aw += v * lw[c];
    ah += v * lh[c];
  }
  part_w[c_off][s4] = (float4){aw.x, aw.y, aw.z, aw.w};
  part_h[c_off][s4] = (float4){ah.x, ah.y, ah.z, ah.w};
  __syncthreads();

  if (t < 8) {
    const float scale_w = gw[0] * rsqrtf(vw[0] + BN_EPS);
    const float shift_w = (bw[0] - mw[0]) * scale_w + betw[0];
    const float scale_h = gh[0] * rsqrtf(vh[0] + BN_EPS);
    const float shift_h = (bh[0] - mh[0]) * scale_h + beth[0];

    float4 cw = {0.f, 0.f, 0.f, 0.f};
    float4 ch = {0.f, 0.f, 0.f, 0.f};
#pragma unroll
    for (int g = 0; g < 32; ++g) {
      const float4 pw = part_w[g][t];
      const float4 ph = part_h[g][t];
      cw.x += pw.x; cw.y += pw.y; cw.z += pw.z; cw.w += pw.w;
      ch.x += ph.x; ch.y += ph.y; ch.z += ph.z; ch.w += ph.w;
    }
    float aws = fmaxf(fmaf(cw.x, scale_w, shift_w), 0.f) +
                fmaxf(fmaf(cw.y, scale_w, shift_w), 0.f) +
                fmaxf(fmaf(cw.z, scale_w, shift_w), 0.f) +
                fmaxf(fmaf(cw.w, scale_w, shift_w), 0.f);
    const float ahs = fmaxf(fmaf(ch.x, scale_h, shift_h), 0.f) +
                      fmaxf(fmaf(ch.y, scale_h, shift_h), 0.f) +
                      fmaxf(fmaf(ch.z, scale_h, shift_h), 0.f) +
                      fmaxf(fmaf(ch.w, scale_h, shift_h), 0.f);
    // lane t (<8) covers h = 4t..4t+3 -> kh = t>>2
    const int kh = t >> 2;
    float v0 = kh == 0 ? ahs : 0.f;
    float v1 = kh == 1 ? ahs : 0.f;
#pragma unroll
    for (int off = 4; off >= 1; off >>= 1) {
      aws += __shfl_xor(aws, off);
      v0 += __shfl_xor(v0, off);
      v1 += __shfl_xor(v1, off);
    }
    if (t == 0) {
      part[b * 32 + row] = (float4){aws, v0, v1, 0.f};  // plain store
    }
  }
}

// One block per batch: reduce 32 row-partials, softmax, emit factors.
__global__ __launch_bounds__(64) void k_factors(
    const float4* __restrict__ part, float2* __restrict__ fac) {
  const int b = blockIdx.x;
  const int l = threadIdx.x;  // 0..63
  float sw0 = 0.f, sw1 = 0.f, h0 = 0.f, h1 = 0.f;
  if (l < 32) {
    const float4 p = part[b * 32 + l];
    if (l < 16) sw0 = p.x; else sw1 = p.x;
    h0 = p.y;
    h1 = p.z;
  }
#pragma unroll
  for (int off = 32; off >= 1; off >>= 1) {
    sw0 += __shfl_xor(sw0, off);
    sw1 += __shfl_xor(sw1, off);
    h0 += __shfl_xor(h0, off);
    h1 += __shfl_xor(h1, off);
  }
  if (l == 0) {
    const float pw0 = sw0 * (1.f / 512.f), pw1 = sw1 * (1.f / 512.f);
    const float ph0 = h0 * (1.f / 512.f), ph1 = h1 * (1.f / 512.f);
    const float mwv = fmaxf(pw0, pw1);
    const float ew0 = __expf(pw0 - mwv), ew1 = __expf(pw1 - mwv);
    const float s0 = ew0 / (ew0 + ew1), s1 = ew1 / (ew0 + ew1);
    const float mhv = fmaxf(ph0, ph1);
    const float eh0 = __expf(ph0 - mhv), eh1 = __expf(ph1 - mhv);
    const float t0 = eh0 / (eh0 + eh1), t1 = eh1 / (eh0 + eh1);
    float f[4];
    f[0] = s0 * t0;
    f[1] = s0 * t1;
    f[2] = s1 * t0;
    f[3] = s1 * t1;
    const float thr = fmaxf(fmaxf(f[0], f[1]), fmaxf(f[2], f[3])) * 0.95f;
#pragma unroll
    for (int q = 0; q < 4; ++q) {
      fac[b * 4 + q] =
          make_float2(1.f + ALPHA * f[q], (f[q] < thr) ? 1.f : BETA);
    }
  }
}

// Elementwise output pass. 8192 blocks x 256 threads; each block owns a
// CONTIGUOUS 1024-float4 (16 KB) span of fm: i = blk*1024 + k*256 + t.
// -> 3 contiguous address streams per block (1 read + 2 NT-write) instead of
// 12 scattered ones; batch = blk>>8 is block-uniform, kw/kh depend only on t,
// so one fac load per thread. 4 NT loads batched ahead of 8 NT stores.
__global__ __launch_bounds__(256) void k_out(
    const float* __restrict__ fm, const float2* __restrict__ fac,
    float* __restrict__ out0, float* __restrict__ out1) {
  const int t = threadIdx.x;
  const int blk = blockIdx.x;
  // i = blk*1024 + k*256 + t ; e = 4i.
  // b = i>>18 = blk>>8 (block-uniform); kw = bit7(i) = bit7(t);
  // kh = bit2(i) = bit2(t).
  const int idx = ((blk >> 8) << 2) | (((t >> 7) & 1) << 1) | ((t >> 2) & 1);
  const float2 f = fac[idx];
  const size_t base = (size_t)blk * 1024 + t;
  const vfloat4* fm4 = reinterpret_cast<const vfloat4*>(fm);
  vfloat4* o0 = reinterpret_cast<vfloat4*>(out0);
  vfloat4* o1 = reinterpret_cast<vfloat4*>(out1);

  const vfloat4 v0 = __builtin_nontemporal_load(&fm4[base + 0 * 256]);
  const vfloat4 v1 = __builtin_nontemporal_load(&fm4[base + 1 * 256]);
  const vfloat4 v2 = __builtin_nontemporal_load(&fm4[base + 2 * 256]);
  const vfloat4 v3 = __builtin_nontemporal_load(&fm4[base + 3 * 256]);

  __builtin_nontemporal_store(v0 * f.x, &o0[base + 0 * 256]);
  __builtin_nontemporal_store(v1 * f.x, &o0[base + 1 * 256]);
  __builtin_nontemporal_store(v2 * f.x, &o0[base + 2 * 256]);
  __builtin_nontemporal_store(v3 * f.x, &o0[base + 3 * 256]);
  __builtin_nontemporal_store(v0 * f.y, &o1[base + 0 * 256]);
  __builtin_nontemporal_store(v1 * f.y, &o1[base + 1 * 256]);
  __builtin_nontemporal_store(v2 * f.y, &o1[base + 2 * 256]);
  __builtin_nontemporal_store(v3 * f.y, &o1[base + 3 * 256]);
}

extern "C" void kernel_launch(void* const* d_in, const int* in_sizes, int n_in,
                              void* d_out, int out_size, void* d_ws,
                              size_t ws_size, hipStream_t stream) {
  const float* fm = (const float*)d_in[0];
  const float* w_w = (const float*)d_in[1];
  const float* b_w = (const float*)d_in[2];
  const float* g_w = (const float*)d_in[3];
  const float* be_w = (const float*)d_in[4];
  const float* m_w = (const float*)d_in[5];
  const float* v_w = (const float*)d_in[6];
  const float* w_h = (const float*)d_in[7];
  const float* b_h = (const float*)d_in[8];
  const float* g_h = (const float*)d_in[9];
  const float* be_h = (const float*)d_in[10];
  const float* m_h = (const float*)d_in[11];
  const float* v_h = (const float*)d_in[12];

  char* ws = (char*)d_ws;
  float4* part = (float4*)(ws + 0);       // 16 KB, fully rewritten each call
  float2* fac = (float2*)(ws + 16384);    // 1 KB, fully rewritten each call

  float* out0 = (float*)d_out;
  float* out1 = out0 + (size_t)32 * 1024 * 1024;

  k_conv<<<32 * 32, 256, 0, stream>>>(fm, w_w, w_h, b_w, g_w, be_w, m_w, v_w,
                                      b_h, g_h, be_h, m_h, v_h, part);
  k_factors<<<32, 64, 0, stream>>>(part, fac);
  k_out<<<8192, 256, 0, stream>>>(fm, fac, out0, out1);
}

// Round 10
// 88.307 us; speedup vs baseline: 2.6224x; 1.0574x over previous
//
#include <hip/hip_runtime.h>

#define BN_EPS 1e-5f
#define ALPHA 0.5f
#define BETA 0.5f

// B=32, C=1024, W=32, H=32, K=2.
// 3 dispatches, no memset, no atomics:
//   k_conv    : conv(C->1) + BN + ReLU + per-(b,row) partial strip sums,
//               one plain float4 store per block -> part[b*32+row]
//   k_factors : per-batch reduce of 32 row-partials + 2-way softmaxes ->
//               fac[b][4] = (boost, mask)
//   k_out     : elementwise, PLAIN loads (probe: let the fm re-read hit the
//               MALL that conv's loads populated) + NT stores (A/B proven)
//
// ws byte layout:
//   part [32*32] float4 @ 0      (16 KB)  {row_w_sum, h0_sum, h1_sum, 0}
//   fac  [32][4] float2 @ 16384  (1 KB)

typedef float vfloat4 __attribute__((ext_vector_type(4)));

__global__ __launch_bounds__(256) void k_conv(
    const float* __restrict__ fm, const float* __restrict__ wW,
    const float* __restrict__ wH, const float* __restrict__ bw,
    const float* __restrict__ gw, const float* __restrict__ betw,
    const float* __restrict__ mw, const float* __restrict__ vw,
    const float* __restrict__ bh, const float* __restrict__ gh,
    const float* __restrict__ beth, const float* __restrict__ mh,
    const float* __restrict__ vh, float4* __restrict__ part) {
  __shared__ float lw[1024];
  __shared__ float lh[1024];
  __shared__ float4 part_w[32][8];
  __shared__ float4 part_h[32][8];

  const int t = threadIdx.x;
  const int b = blockIdx.x >> 5;    // batch
  const int row = blockIdx.x & 31;  // w row

  {
    reinterpret_cast<float4*>(lw)[t] = reinterpret_cast<const float4*>(wW)[t];
    reinterpret_cast<float4*>(lh)[t] = reinterpret_cast<const float4*>(wH)[t];
  }
  __syncthreads();

  const int c_off = t >> 3;  // channel within 32-group
  const int s4 = t & 7;      // float4 within the row (h)
  const vfloat4* f4 = reinterpret_cast<const vfloat4*>(fm) +
                      ((size_t)(b * 1024 + c_off) * 256 + row * 8 + s4);

  vfloat4 aw = {0.f, 0.f, 0.f, 0.f};
  vfloat4 ah = {0.f, 0.f, 0.f, 0.f};
#pragma unroll 8
  for (int it = 0; it < 32; ++it) {
    const int c = it * 32 + c_off;
    const vfloat4 v = f4[(size_t)it * 32 * 256];
    aw += v * lw[c];
    ah += v * lh[c];
  }
  part_w[c_off][s4] = (float4){aw.x, aw.y, aw.z, aw.w};
  part_h[c_off][s4] = (float4){ah.x, ah.y, ah.z, ah.w};
  __syncthreads();

  if (t < 8) {
    const float scale_w = gw[0] * rsqrtf(vw[0] + BN_EPS);
    const float shift_w = (bw[0] - mw[0]) * scale_w + betw[0];
    const float scale_h = gh[0] * rsqrtf(vh[0] + BN_EPS);
    const float shift_h = (bh[0] - mh[0]) * scale_h + beth[0];

    float4 cw = {0.f, 0.f, 0.f, 0.f};
    float4 ch = {0.f, 0.f, 0.f, 0.f};
#pragma unroll
    for (int g = 0; g < 32; ++g) {
      const float4 pw = part_w[g][t];
      const float4 ph = part_h[g][t];
      cw.x += pw.x; cw.y += pw.y; cw.z += pw.z; cw.w += pw.w;
      ch.x += ph.x; ch.y += ph.y; ch.z += ph.z; ch.w += ph.w;
    }
    float aws = fmaxf(fmaf(cw.x, scale_w, shift_w), 0.f) +
                fmaxf(fmaf(cw.y, scale_w, shift_w), 0.f) +
                fmaxf(fmaf(cw.z, scale_w, shift_w), 0.f) +
                fmaxf(fmaf(cw.w, scale_w, shift_w), 0.f);
    const float ahs = fmaxf(fmaf(ch.x, scale_h, shift_h), 0.f) +
                      fmaxf(fmaf(ch.y, scale_h, shift_h), 0.f) +
                      fmaxf(fmaf(ch.z, scale_h, shift_h), 0.f) +
                      fmaxf(fmaf(ch.w, scale_h, shift_h), 0.f);
    // lane t (<8) covers h = 4t..4t+3 -> kh = t>>2
    const int kh = t >> 2;
    float v0 = kh == 0 ? ahs : 0.f;
    float v1 = kh == 1 ? ahs : 0.f;
#pragma unroll
    for (int off = 4; off >= 1; off >>= 1) {
      aws += __shfl_xor(aws, off);
      v0 += __shfl_xor(v0, off);
      v1 += __shfl_xor(v1, off);
    }
    if (t == 0) {
      part[b * 32 + row] = (float4){aws, v0, v1, 0.f};  // plain store
    }
  }
}

// One block per batch: reduce 32 row-partials, softmax, emit factors.
__global__ __launch_bounds__(64) void k_factors(
    const float4* __restrict__ part, float2* __restrict__ fac) {
  const int b = blockIdx.x;
  const int l = threadIdx.x;  // 0..63
  float sw0 = 0.f, sw1 = 0.f, h0 = 0.f, h1 = 0.f;
  if (l < 32) {
    const float4 p = part[b * 32 + l];
    if (l < 16) sw0 = p.x; else sw1 = p.x;
    h0 = p.y;
    h1 = p.z;
  }
#pragma unroll
  for (int off = 32; off >= 1; off >>= 1) {
    sw0 += __shfl_xor(sw0, off);
    sw1 += __shfl_xor(sw1, off);
    h0 += __shfl_xor(h0, off);
    h1 += __shfl_xor(h1, off);
  }
  if (l == 0) {
    const float pw0 = sw0 * (1.f / 512.f), pw1 = sw1 * (1.f / 512.f);
    const float ph0 = h0 * (1.f / 512.f), ph1 = h1 * (1.f / 512.f);
    const float mwv = fmaxf(pw0, pw1);
    const float ew0 = __expf(pw0 - mwv), ew1 = __expf(pw1 - mwv);
    const float s0 = ew0 / (ew0 + ew1), s1 = ew1 / (ew0 + ew1);
    const float mhv = fmaxf(ph0, ph1);
    const float eh0 = __expf(ph0 - mhv), eh1 = __expf(ph1 - mhv);
    const float t0 = eh0 / (eh0 + eh1), t1 = eh1 / (eh0 + eh1);
    float f[4];
    f[0] = s0 * t0;
    f[1] = s0 * t1;
    f[2] = s1 * t0;
    f[3] = s1 * t1;
    const float thr = fmaxf(fmaxf(f[0], f[1]), fmaxf(f[2], f[3])) * 0.95f;
#pragma unroll
    for (int q = 0; q < 4; ++q) {
      fac[b * 4 + q] =
          make_float2(1.f + ALPHA * f[q], (f[q] < thr) ? 1.f : BETA);
    }
  }
}

// Elementwise output pass. 8192 blocks x 256 threads; each block owns a
// CONTIGUOUS 1024-float4 (16 KB) span of fm: i = blk*1024 + k*256 + t.
// PLAIN loads this round (probe: MALL hit on the fm re-read); NT stores.
__global__ __launch_bounds__(256) void k_out(
    const float* __restrict__ fm, const float2* __restrict__ fac,
    float* __restrict__ out0, float* __restrict__ out1) {
  const int t = threadIdx.x;
  const int blk = blockIdx.x;
  // i = blk*1024 + k*256 + t ; e = 4i.
  // b = i>>18 = blk>>8 (block-uniform); kw = bit7(i) = bit7(t);
  // kh = bit2(i) = bit2(t).
  const int idx = ((blk >> 8) << 2) | (((t >> 7) & 1) << 1) | ((t >> 2) & 1);
  const float2 f = fac[idx];
  const size_t base = (size_t)blk * 1024 + t;
  const vfloat4* fm4 = reinterpret_cast<const vfloat4*>(fm);
  vfloat4* o0 = reinterpret_cast<vfloat4*>(out0);
  vfloat4* o1 = reinterpret_cast<vfloat4*>(out1);

  const vfloat4 v0 = fm4[base + 0 * 256];
  const vfloat4 v1 = fm4[base + 1 * 256];
  const vfloat4 v2 = fm4[base + 2 * 256];
  const vfloat4 v3 = fm4[base + 3 * 256];

  __builtin_nontemporal_store(v0 * f.x, &o0[base + 0 * 256]);
  __builtin_nontemporal_store(v1 * f.x, &o0[base + 1 * 256]);
  __builtin_nontemporal_store(v2 * f.x, &o0[base + 2 * 256]);
  __builtin_nontemporal_store(v3 * f.x, &o0[base + 3 * 256]);
  __builtin_nontemporal_store(v0 * f.y, &o1[base + 0 * 256]);
  __builtin_nontemporal_store(v1 * f.y, &o1[base + 1 * 256]);
  __builtin_nontemporal_store(v2 * f.y, &o1[base + 2 * 256]);
  __builtin_nontemporal_store(v3 * f.y, &o1[base + 3 * 256]);
}

extern "C" void kernel_launch(void* const* d_in, const int* in_sizes, int n_in,
                              void* d_out, int out_size, void* d_ws,
                              size_t ws_size, hipStream_t stream) {
  const float* fm = (const float*)d_in[0];
  const float* w_w = (const float*)d_in[1];
  const float* b_w = (const float*)d_in[2];
  const float* g_w = (const float*)d_in[3];
  const float* be_w = (const float*)d_in[4];
  const float* m_w = (const float*)d_in[5];
  const float* v_w = (const float*)d_in[6];
  const float* w_h = (const float*)d_in[7];
  const float* b_h = (const float*)d_in[8];
  const float* g_h = (const float*)d_in[9];
  const float* be_h = (const float*)d_in[10];
  const float* m_h = (const float*)d_in[11];
  const float* v_h = (const float*)d_in[12];

  char* ws = (char*)d_ws;
  float4* part = (float4*)(ws + 0);       // 16 KB, fully rewritten each call
  float2* fac = (float2*)(ws + 16384);    // 1 KB, fully rewritten each call

  float* out0 = (float*)d_out;
  float* out1 = out0 + (size_t)32 * 1024 * 1024;

  k_conv<<<32 * 32, 256, 0, stream>>>(fm, w_w, w_h, b_w, g_w, be_w, m_w, v_w,
                                      b_h, g_h, be_h, m_h, v_h, part);
  k_factors<<<32, 64, 0, stream>>>(part, fac);
  k_out<<<8192, 256, 0, stream>>>(fm, fac, out0, out1);
}

// Round 11
// 85.878 us; speedup vs baseline: 2.6966x; 1.0283x over previous
//
#include <hip/hip_runtime.h>

#define BN_EPS 1e-5f
#define ALPHA 0.5f
#define BETA 0.5f

// B=32, C=1024, W=32, H=32, K=2.
// 2 dispatches, no memset, no atomics:
//   k_conv : conv(C->1) + BN + ReLU + per-(b,row) partial strip sums,
//            one plain float4 store per block -> part[b*32+row]
//   k_out  : each WAVE recomputes its batch's softmax factors from the 32
//            row-partials (512 B, butterfly reduce), then elementwise pass:
//            plain loads (MALL hit on fm re-read), NT stores, contiguous
//            16 KB span per block.
//
// ws byte layout:
//   part [32*32] float4 @ 0  (16 KB)  {row_w_sum, h0_sum, h1_sum, 0}

typedef float vfloat4 __attribute__((ext_vector_type(4)));

__global__ __launch_bounds__(256) void k_conv(
    const float* __restrict__ fm, const float* __restrict__ wW,
    const float* __restrict__ wH, const float* __restrict__ bw,
    const float* __restrict__ gw, const float* __restrict__ betw,
    const float* __restrict__ mw, const float* __restrict__ vw,
    const float* __restrict__ bh, const float* __restrict__ gh,
    const float* __restrict__ beth, const float* __restrict__ mh,
    const float* __restrict__ vh, float4* __restrict__ part) {
  __shared__ float lw[1024];
  __shared__ float lh[1024];
  __shared__ float4 part_w[32][8];
  __shared__ float4 part_h[32][8];

  const int t = threadIdx.x;
  const int b = blockIdx.x >> 5;    // batch
  const int row = blockIdx.x & 31;  // w row

  {
    reinterpret_cast<float4*>(lw)[t] = reinterpret_cast<const float4*>(wW)[t];
    reinterpret_cast<float4*>(lh)[t] = reinterpret_cast<const float4*>(wH)[t];
  }
  __syncthreads();

  const int c_off = t >> 3;  // channel within 32-group
  const int s4 = t & 7;      // float4 within the row (h)
  const vfloat4* f4 = reinterpret_cast<const vfloat4*>(fm) +
                      ((size_t)(b * 1024 + c_off) * 256 + row * 8 + s4);

  vfloat4 aw = {0.f, 0.f, 0.f, 0.f};
  vfloat4 ah = {0.f, 0.f, 0.f, 0.f};
#pragma unroll 8
  for (int it = 0; it < 32; ++it) {
    const int c = it * 32 + c_off;
    const vfloat4 v = f4[(size_t)it * 32 * 256];
    aw += v * lw[c];
    ah += v * lh[c];
  }
  part_w[c_off][s4] = (float4){aw.x, aw.y, aw.z, aw.w};
  part_h[c_off][s4] = (float4){ah.x, ah.y, ah.z, ah.w};
  __syncthreads();

  if (t < 8) {
    const float scale_w = gw[0] * rsqrtf(vw[0] + BN_EPS);
    const float shift_w = (bw[0] - mw[0]) * scale_w + betw[0];
    const float scale_h = gh[0] * rsqrtf(vh[0] + BN_EPS);
    const float shift_h = (bh[0] - mh[0]) * scale_h + beth[0];

    float4 cw = {0.f, 0.f, 0.f, 0.f};
    float4 ch = {0.f, 0.f, 0.f, 0.f};
#pragma unroll
    for (int g = 0; g < 32; ++g) {
      const float4 pw = part_w[g][t];
      const float4 ph = part_h[g][t];
      cw.x += pw.x; cw.y += pw.y; cw.z += pw.z; cw.w += pw.w;
      ch.x += ph.x; ch.y += ph.y; ch.z += ph.z; ch.w += ph.w;
    }
    float aws = fmaxf(fmaf(cw.x, scale_w, shift_w), 0.f) +
                fmaxf(fmaf(cw.y, scale_w, shift_w), 0.f) +
                fmaxf(fmaf(cw.z, scale_w, shift_w), 0.f) +
                fmaxf(fmaf(cw.w, scale_w, shift_w), 0.f);
    const float ahs = fmaxf(fmaf(ch.x, scale_h, shift_h), 0.f) +
                      fmaxf(fmaf(ch.y, scale_h, shift_h), 0.f) +
                      fmaxf(fmaf(ch.z, scale_h, shift_h), 0.f) +
                      fmaxf(fmaf(ch.w, scale_h, shift_h), 0.f);
    // lane t (<8) covers h = 4t..4t+3 -> kh = t>>2
    const int kh = t >> 2;
    float v0 = kh == 0 ? ahs : 0.f;
    float v1 = kh == 1 ? ahs : 0.f;
#pragma unroll
    for (int off = 4; off >= 1; off >>= 1) {
      aws += __shfl_xor(aws, off);
      v0 += __shfl_xor(v0, off);
      v1 += __shfl_xor(v1, off);
    }
    if (t == 0) {
      part[b * 32 + row] = (float4){aws, v0, v1, 0.f};  // plain store
    }
  }
}

// Elementwise output pass, 8192 blocks x 256 threads, contiguous 16 KB span
// per block. Each wave recomputes its batch's factors from part[] (512 B):
// butterfly shfl_xor gives every lane the 4 pooled sums; each lane evaluates
// the softmaxes redundantly and selects (boost, mask) by its (kw, kh).
__global__ __launch_bounds__(256) void k_out(
    const float* __restrict__ fm, const float4* __restrict__ part,
    float* __restrict__ out0, float* __restrict__ out1) {
  const int t = threadIdx.x;
  const int blk = blockIdx.x;
  const int b = blk >> 8;  // block-uniform batch
  const size_t base = (size_t)blk * 1024 + t;
  const vfloat4* fm4 = reinterpret_cast<const vfloat4*>(fm);
  vfloat4* o0 = reinterpret_cast<vfloat4*>(out0);
  vfloat4* o1 = reinterpret_cast<vfloat4*>(out1);

  // issue the 4 main loads first so they overlap the factor computation
  const vfloat4 v0 = fm4[base + 0 * 256];
  const vfloat4 v1 = fm4[base + 1 * 256];
  const vfloat4 v2 = fm4[base + 2 * 256];
  const vfloat4 v3 = fm4[base + 3 * 256];

  // ---- per-wave factor recomputation ----
  const int l = t & 63;
  float sw0 = 0.f, sw1 = 0.f, h0 = 0.f, h1 = 0.f;
  if (l < 32) {
    const float4 p = part[b * 32 + l];
    if (l < 16) sw0 = p.x; else sw1 = p.x;
    h0 = p.y;
    h1 = p.z;
  }
#pragma unroll
  for (int off = 32; off >= 1; off >>= 1) {
    sw0 += __shfl_xor(sw0, off);
    sw1 += __shfl_xor(sw1, off);
    h0 += __shfl_xor(h0, off);
    h1 += __shfl_xor(h1, off);
  }
  const float pw0 = sw0 * (1.f / 512.f), pw1 = sw1 * (1.f / 512.f);
  const float ph0 = h0 * (1.f / 512.f), ph1 = h1 * (1.f / 512.f);
  const float mwv = fmaxf(pw0, pw1);
  const float ew0 = __expf(pw0 - mwv), ew1 = __expf(pw1 - mwv);
  const float s0 = ew0 / (ew0 + ew1), s1 = ew1 / (ew0 + ew1);
  const float mhv = fmaxf(ph0, ph1);
  const float eh0 = __expf(ph0 - mhv), eh1 = __expf(ph1 - mhv);
  const float t0 = eh0 / (eh0 + eh1), t1 = eh1 / (eh0 + eh1);
  const float f00 = s0 * t0, f01 = s0 * t1, f10 = s1 * t0, f11 = s1 * t1;
  const float thr = fmaxf(fmaxf(f00, f01), fmaxf(f10, f11)) * 0.95f;
  // i = blk*1024 + k*256 + t: kw = bit7(t), kh = bit2(t)
  const int kw = (t >> 7) & 1;
  const int kh = (t >> 2) & 1;
  const float fq = kw ? (kh ? f11 : f10) : (kh ? f01 : f00);
  const float boost = 1.f + ALPHA * fq;
  const float mask = (fq < thr) ? 1.f : BETA;

  __builtin_nontemporal_store(v0 * boost, &o0[base + 0 * 256]);
  __builtin_nontemporal_store(v1 * boost, &o0[base + 1 * 256]);
  __builtin_nontemporal_store(v2 * boost, &o0[base + 2 * 256]);
  __builtin_nontemporal_store(v3 * boost, &o0[base + 3 * 256]);
  __builtin_nontemporal_store(v0 * mask, &o1[base + 0 * 256]);
  __builtin_nontemporal_store(v1 * mask, &o1[base + 1 * 256]);
  __builtin_nontemporal_store(v2 * mask, &o1[base + 2 * 256]);
  __builtin_nontemporal_store(v3 * mask, &o1[base + 3 * 256]);
}

extern "C" void kernel_launch(void* const* d_in, const int* in_sizes, int n_in,
                              void* d_out, int out_size, void* d_ws,
                              size_t ws_size, hipStream_t stream) {
  const float* fm = (const float*)d_in[0];
  const float* w_w = (const float*)d_in[1];
  const float* b_w = (const float*)d_in[2];
  const float* g_w = (const float*)d_in[3];
  const float* be_w = (const float*)d_in[4];
  const float* m_w = (const float*)d_in[5];
  const float* v_w = (const float*)d_in[6];
  const float* w_h = (const float*)d_in[7];
  const float* b_h = (const float*)d_in[8];
  const float* g_h = (const float*)d_in[9];
  const float* be_h = (const float*)d_in[10];
  const float* m_h = (const float*)d_in[11];
  const float* v_h = (const float*)d_in[12];

  char* ws = (char*)d_ws;
  float4* part = (float4*)(ws + 0);  // 16 KB, fully rewritten each call

  float* out0 = (float*)d_out;
  float* out1 = out0 + (size_t)32 * 1024 * 1024;

  k_conv<<<32 * 32, 256, 0, stream>>>(fm, w_w, w_h, b_w, g_w, be_w, m_w, v_w,
                                      b_h, g_h, be_h, m_h, v_h, part);
  k_out<<<8192, 256, 0, stream>>>(fm, part, out0, out1);
}